// Round 6
// baseline (266.110 us; speedup 1.0000x reference)
//
#include <hip/hip_runtime.h>
#include <hip/hip_bf16.h>
#include <stdint.h>

constexpr int BB  = 64;    // batch
constexpr int SS  = 512;   // seq len
constexpr int HH  = 768;   // hidden
constexpr int NL  = 9;     // labels
constexpr int NROWS = BB * SS;          // 32768
constexpr int EMN   = SS * NL;          // 4608 emissions per batch
constexpr int NSEG  = 8;                // time segments for parallel lognorm
constexpr float NEG  = -1e30f;

__device__ __forceinline__ float readlane_f(float v, int lane) {
  union { float f; int i; } u;
  u.f = v;
  u.i = __builtin_amdgcn_readlane(u.i, lane);
  return u.f;
}

// ---------------------------------------------------------------------------
// Kernel 1: logits[b,s,l] = hidden[b,s,:] @ W[:,l] + bias[l]
// One wave per 4 rows. W slice lives in LDS (NOT registers — the R1..R5
// versions spilled ~80 VGPRs under the (256,2) cap, costing ~150 us).
// Per-lane slice layout: wlds[lane*144 + j*48 + k*12 + l] (l padded 9->12):
// 16B-aligned for ds_read_b128, lane stride 144 => 2-way bank alias (free).
// ---------------------------------------------------------------------------
__global__ __launch_bounds__(256, 2) void logits_kernel(
    const float* __restrict__ hidden, const float* __restrict__ W,
    const float* __restrict__ bias, const int* __restrict__ mask,
    float* __restrict__ logits, int* __restrict__ lens) {
  __shared__ float wlds[64 * 144];   // 36.9 KB
  const int tid  = threadIdx.x;
  const int lane = tid & 63;
  const int wid  = blockIdx.x * 4 + (tid >> 6);   // 8192 waves

  if (blockIdx.x < 64 && tid < 64) {
    const int4* mp = (const int4*)(mask + blockIdx.x * SS);
    const int4 a = mp[tid];
    const int4 c = mp[tid + 64];
    int lsum = a.x + a.y + a.z + a.w + c.x + c.y + c.z + c.w;
#pragma unroll
    for (int off = 32; off >= 1; off >>= 1) lsum += __shfl_xor(lsum, off, 64);
    if (tid == 0) lens[blockIdx.x] = lsum;
  }

  // Stage W into the per-lane slice layout. W element (e, l), e = 4*ln+256*j+k.
  for (int it = tid; it < HH * NL; it += 256) {
    const int e = it / NL, l = it - e * NL;
    const int ln = (e & 255) >> 2, j = e >> 8, k = e & 3;
    wlds[ln * 144 + j * 48 + k * 12 + l] = W[it];
  }
  __syncthreads();
  const float my_bias = (lane < NL) ? bias[lane] : 0.0f;
  const float* wbase = wlds + lane * 144;

  float4 h[4][3];
#pragma unroll
  for (int r = 0; r < 4; ++r) {
    const float4* hp = (const float4*)(hidden + (size_t)(wid + r * 8192) * HH);
#pragma unroll
    for (int j = 0; j < 3; ++j) h[r][j] = hp[lane + j * 64];
  }
  float acc[4][NL];
#pragma unroll
  for (int r = 0; r < 4; ++r)
#pragma unroll
    for (int l = 0; l < NL; ++l) acc[r][l] = 0.0f;

#pragma unroll
  for (int j = 0; j < 3; ++j) {
    // l-quads 0..3 and 4..7 via b128 reads; l=8 via scalars. Expression shape
    // per (r,l) matches R5 exactly: acc += hx*w0 + hy*w1 + hz*w2 + hw*w3.
#pragma unroll
    for (int lq = 0; lq < 2; ++lq) {
      const float4 w0 = *(const float4*)(wbase + j * 48 + 0 * 12 + lq * 4);
      const float4 w1 = *(const float4*)(wbase + j * 48 + 1 * 12 + lq * 4);
      const float4 w2 = *(const float4*)(wbase + j * 48 + 2 * 12 + lq * 4);
      const float4 w3 = *(const float4*)(wbase + j * 48 + 3 * 12 + lq * 4);
#pragma unroll
      for (int r = 0; r < 4; ++r) {
        const float4 hv = h[r][j];
        acc[r][lq * 4 + 0] += hv.x * w0.x + hv.y * w1.x + hv.z * w2.x + hv.w * w3.x;
        acc[r][lq * 4 + 1] += hv.x * w0.y + hv.y * w1.y + hv.z * w2.y + hv.w * w3.y;
        acc[r][lq * 4 + 2] += hv.x * w0.z + hv.y * w1.z + hv.z * w2.z + hv.w * w3.z;
        acc[r][lq * 4 + 3] += hv.x * w0.w + hv.y * w1.w + hv.z * w2.w + hv.w * w3.w;
      }
    }
    const float w80 = wbase[j * 48 + 0 * 12 + 8];
    const float w81 = wbase[j * 48 + 1 * 12 + 8];
    const float w82 = wbase[j * 48 + 2 * 12 + 8];
    const float w83 = wbase[j * 48 + 3 * 12 + 8];
#pragma unroll
    for (int r = 0; r < 4; ++r) {
      const float4 hv = h[r][j];
      acc[r][8] += hv.x * w80 + hv.y * w81 + hv.z * w82 + hv.w * w83;
    }
  }
#pragma unroll
  for (int off = 32; off >= 1; off >>= 1)
#pragma unroll
    for (int r = 0; r < 4; ++r)
#pragma unroll
      for (int l = 0; l < NL; ++l)
        acc[r][l] += __shfl_xor(acc[r][l], off, 64);
  if (lane < NL) {
#pragma unroll
    for (int r = 0; r < 4; ++r) {
      float v = acc[r][0];
#pragma unroll
      for (int l = 1; l < NL; ++l) if (lane == l) v = acc[r][l];
      logits[(size_t)(wid + r * 8192) * NL + lane] = v + my_bias;
    }
  }
}

// ---------------------------------------------------------------------------
// Kernel 2: scan kernel, 1664 one-wave blocks.
//   blk   0..  63 : viterbi (bit-exact ref arithmetic), em staged in LDS
//   blk  64.. 127 : numerator (gold-path score), parallel over t
//   blk 128..1663 : lognorm segment scans, 3 basis chains per wave
// ---------------------------------------------------------------------------
__global__ __launch_bounds__(64) void scan_kernel(
    const float* __restrict__ logits, const int* __restrict__ labels,
    const float* __restrict__ start_t, const float* __restrict__ end_t,
    const float* __restrict__ trans, float* __restrict__ out,
    float* __restrict__ num_den, const int* __restrict__ lens,
    float* __restrict__ segmat) {
  __shared__ __align__(16) float em_s[EMN + 64];   // pad: +4-step prefetch
  __shared__ unsigned char bp_s[EMN + 80];
  __shared__ unsigned char tags_s[SS];
  __shared__ int lab[SS];

  const int blk = blockIdx.x;
  const int tid = threadIdx.x;
  const int j   = (tid < NL) ? tid : NL - 1;

  if (blk < 64) {
    // ================= viterbi =================
    const int b   = blk;
    const int len = lens[b];
    // stage emissions to LDS (coalesced float4) — removes vmem latency from
    // the serial chain (R4/R5 read em from global: ~420 cyc/step)
    {
      const float4* src = (const float4*)(logits + (size_t)b * EMN);
      float4* dst = (float4*)em_s;
      for (int i = tid; i < EMN / 4; i += 64) dst[i] = src[i];
    }
    float tc[NL];
#pragma unroll
    for (int i = 0; i < NL; ++i) tc[i] = trans[i * NL + j];
    __syncthreads();
    float s[NL];
#pragma unroll
    for (int i = 0; i < NL; ++i) s[i] = start_t[i] + em_s[i];
    float eA = em_s[1 * NL + j], eB = em_s[2 * NL + j];
    float eC = em_s[3 * NL + j], eD = em_s[4 * NL + j];
    for (int t = 1; t < len; ++t) {
      float c[NL];
#pragma unroll
      for (int i = 0; i < NL; ++i) c[i] = s[i] + tc[i];
      // exact max (order-free), then first-max arg via equality mask
      const float x01 = fmaxf(c[0], c[1]), x23 = fmaxf(c[2], c[3]);
      const float x45 = fmaxf(c[4], c[5]), x67 = fmaxf(c[6], c[7]);
      const float best = fmaxf(fmaxf(fmaxf(x01, x23), fmaxf(x45, x67)), c[8]);
      const float nxt = best + eA;
      uint32_t eq = 0;
#pragma unroll
      for (int i = 0; i < NL; ++i) eq |= (c[i] == best) ? (1u << i) : 0u;
      bp_s[t * NL + tid] = (unsigned char)(__ffs(eq) - 1);
#pragma unroll
      for (int i = 0; i < NL; ++i) s[i] = readlane_f(nxt, i);
      eA = eB; eB = eC; eC = eD;
      eD = em_s[(t + 4) * NL + j];   // pad-safe
    }
    float bv = s[0] + end_t[0];
    int   bl = 0;
#pragma unroll
    for (int i = 1; i < NL; ++i) {
      const float cc = s[i] + end_t[i];
      if (cc > bv) { bv = cc; bl = i; }
    }
    __syncthreads();

    // backtrace: chunked map composition (verified R3..R5)
    uint64_t C = 0x876543210ULL;
#pragma unroll
    for (int k = 1; k <= 8; ++k) {
      const int t = 8 * tid + k;
      uint64_t nc = 0;
#pragma unroll
      for (int x = 0; x < 9; ++x) {
        const int g = bp_s[t * NL + x] & 15;
        nc |= ((C >> (4 * g)) & 15ULL) << (4 * x);
      }
      C = (t < len) ? nc : C;
    }
    const uint32_t Clo = (uint32_t)C, Chi = (uint32_t)(C >> 32);
    uint32_t cur = (uint32_t)bl;
    int bnd = 0;
#pragma unroll
    for (int c = 63; c >= 0; --c) {
      bnd = (tid == c) ? (int)cur : bnd;
      const uint32_t lo = (uint32_t)__builtin_amdgcn_readlane((int)Clo, c);
      const uint32_t hi = (uint32_t)__builtin_amdgcn_readlane((int)Chi, c);
      const uint64_t cc = ((uint64_t)hi << 32) | lo;
      cur = (uint32_t)((cc >> (4 * cur)) & 15u);
    }
    int tag = bnd;
#pragma unroll
    for (int k = 8; k >= 1; --k) {
      const int t = 8 * tid + k;
      const int tt = (t < 512) ? t : 511;
      const int nt = bp_s[tt * NL + tag];
      tag = (t < len) ? nt : tag;
      tags_s[t - 1] = (unsigned char)tag;
    }
    __syncthreads();
    for (int i = tid; i < EMN; i += 64) {
      const int t = i / NL;
      const int l = i - t * NL;
      out[1 + (size_t)b * EMN + i] =
          (t < len && l == (int)tags_s[t]) ? 1.0f : 0.0f;
    }

  } else if (blk < 128) {
    // ================= numerator =================
    const int b   = blk - 64;
    const int len = lens[b];
    const float* emb = logits + (size_t)b * EMN;
    for (int t = tid; t < SS; t += 64) {
      const int v = labels[b * SS + t];
      lab[t] = (v == -100) ? 0 : v;
    }
    __syncthreads();
    float contrib = 0.0f;
    for (int t = tid; t < SS; t += 64) {
      if (t >= 1 && t < len)
        contrib += emb[t * NL + lab[t]] + trans[lab[t - 1] * NL + lab[t]];
    }
#pragma unroll
    for (int off = 32; off >= 1; off >>= 1)
      contrib += __shfl_xor(contrib, off, 64);
    if (tid == 0) {
      const int l0 = lab[0];
      num_den[b] = start_t[l0] + emb[l0] + contrib + end_t[lab[len - 1]];
    }

  } else {
    // ================= lognorm segment scan, 3 chains per wave =================
    const int id   = blk - 128;        // 0..1535
    const int pair = id / 3;           // (b, sg)
    const int wv   = id - pair * 3;    // which e-triple
    const int b    = pair >> 3;
    const int sg   = pair & 7;
    const int e0   = 3 * wv;           // chains e0, e0+1, e0+2
    const int len  = lens[b];
    const float* emb = logits + (size_t)b * EMN;
    float tc[NL];
#pragma unroll
    for (int i = 0; i < NL; ++i) tc[i] = trans[i * NL + j];
    float s0[NL], s1[NL], s2[NL];
#pragma unroll
    for (int i = 0; i < NL; ++i) {
      s0[i] = (i == e0)     ? 0.0f : NEG;
      s1[i] = (i == e0 + 1) ? 0.0f : NEG;
      s2[i] = (i == e0 + 2) ? 0.0f : NEG;
    }
    float my0 = (j == e0)     ? 0.0f : NEG;
    float my1 = (j == e0 + 1) ? 0.0f : NEG;
    float my2 = (j == e0 + 2) ? 0.0f : NEG;
    const int tbeg  = 64 * sg + 1;
    const int tlast = (64 * sg + 64 < 511) ? 64 * sg + 64 : 511;
    float eA = emb[tbeg * NL + j],       eB = emb[(tbeg + 1) * NL + j];
    float eC = emb[(tbeg + 2) * NL + j], eD = emb[(tbeg + 3) * NL + j];
    for (int t = tbeg; t <= tlast; ++t) {
      if (t >= len) break;             // prefix mask: rest are identity steps
      float c0[NL], c1[NL], c2[NL];
#pragma unroll
      for (int i = 0; i < NL; ++i) {
        c0[i] = s0[i] + tc[i];
        c1[i] = s1[i] + tc[i];
        c2[i] = s2[i] + tc[i];
      }
      const float m0 = fmaxf(fmaxf(fmaxf(fmaxf(c0[0], c0[1]), fmaxf(c0[2], c0[3])),
                                   fmaxf(fmaxf(c0[4], c0[5]), fmaxf(c0[6], c0[7]))), c0[8]);
      const float m1 = fmaxf(fmaxf(fmaxf(fmaxf(c1[0], c1[1]), fmaxf(c1[2], c1[3])),
                                   fmaxf(fmaxf(c1[4], c1[5]), fmaxf(c1[6], c1[7]))), c1[8]);
      const float m2 = fmaxf(fmaxf(fmaxf(fmaxf(c2[0], c2[1]), fmaxf(c2[2], c2[3])),
                                   fmaxf(fmaxf(c2[4], c2[5]), fmaxf(c2[6], c2[7]))), c2[8]);
      float u0 = 0.0f, u1 = 0.0f, u2 = 0.0f;
#pragma unroll
      for (int i = 0; i < NL; ++i) {
        u0 += __expf(c0[i] - m0);
        u1 += __expf(c1[i] - m1);
        u2 += __expf(c2[i] - m2);
      }
      my0 = m0 + __logf(u0) + eA;
      my1 = m1 + __logf(u1) + eA;
      my2 = m2 + __logf(u2) + eA;
#pragma unroll
      for (int i = 0; i < NL; ++i) {
        s0[i] = readlane_f(my0, i);
        s1[i] = readlane_f(my1, i);
        s2[i] = readlane_f(my2, i);
      }
      eA = eB; eB = eC; eC = eD;
      eD = emb[(t + 4) * NL + j];
    }
    if (tid < NL) {
      float* M = segmat + (size_t)(b * NSEG + sg) * 81;
      M[(e0    ) * NL + tid] = my0;
      M[(e0 + 1) * NL + tid] = my1;
      M[(e0 + 2) * NL + tid] = my2;
    }
  }
}

// ---------------------------------------------------------------------------
// Kernel 3: combine + loss — per batch, chain the 8 segment matrices, get
// den = logsumexp(v + end_t), then atomically accumulate (den-num)/64.
// ---------------------------------------------------------------------------
__global__ __launch_bounds__(64) void combine_kernel(
    const float* __restrict__ logits, const float* __restrict__ segmat,
    const float* __restrict__ start_t, const float* __restrict__ end_t,
    const float* __restrict__ num_den, float* __restrict__ out) {
  const int b   = blockIdx.x;
  const int tid = threadIdx.x;
  const int j   = (tid < NL) ? tid : NL - 1;
  float s[NL];
#pragma unroll
  for (int i = 0; i < NL; ++i) s[i] = start_t[i] + logits[(size_t)b * EMN + i];
  float mcur[NL], mnxt[NL];
  {
    const float* M = segmat + (size_t)(b * NSEG) * 81;
#pragma unroll
    for (int i = 0; i < NL; ++i) mcur[i] = M[i * NL + j];
  }
  for (int sg = 0; sg < NSEG; ++sg) {
    if (sg + 1 < NSEG) {
      const float* M = segmat + (size_t)(b * NSEG + sg + 1) * 81;
#pragma unroll
      for (int i = 0; i < NL; ++i) mnxt[i] = M[i * NL + j];
    }
    float c[NL];
#pragma unroll
    for (int i = 0; i < NL; ++i) c[i] = s[i] + mcur[i];
    const float x01 = fmaxf(c[0], c[1]), x23 = fmaxf(c[2], c[3]);
    const float x45 = fmaxf(c[4], c[5]), x67 = fmaxf(c[6], c[7]);
    const float m = fmaxf(fmaxf(fmaxf(x01, x23), fmaxf(x45, x67)), c[8]);
    float sum = 0.0f;
#pragma unroll
    for (int i = 0; i < NL; ++i) sum += __expf(c[i] - m);
    const float nxt = m + __logf(sum);
#pragma unroll
    for (int i = 0; i < NL; ++i) s[i] = readlane_f(nxt, i);
#pragma unroll
    for (int i = 0; i < NL; ++i) mcur[i] = mnxt[i];
  }
  float c[NL];
#pragma unroll
  for (int i = 0; i < NL; ++i) c[i] = s[i] + end_t[i];
  const float x01 = fmaxf(c[0], c[1]), x23 = fmaxf(c[2], c[3]);
  const float x45 = fmaxf(c[4], c[5]), x67 = fmaxf(c[6], c[7]);
  const float m = fmaxf(fmaxf(fmaxf(x01, x23), fmaxf(x45, x67)), c[8]);
  float sum = 0.0f;
#pragma unroll
  for (int i = 0; i < NL; ++i) sum += __expf(c[i] - m);
  if (tid == 0) {
    const float den = m + __logf(sum);
    atomicAdd(out, (den - num_den[b]) * (1.0f / 64.0f));
  }
}

extern "C" void kernel_launch(void* const* d_in, const int* in_sizes, int n_in,
                              void* d_out, int out_size, void* d_ws, size_t ws_size,
                              hipStream_t stream) {
  const float* hidden  = (const float*)d_in[0];
  const int*   mask    = (const int*)d_in[1];
  const int*   labels  = (const int*)d_in[2];
  const float* W       = (const float*)d_in[3];
  const float* bias    = (const float*)d_in[4];
  const float* start_t = (const float*)d_in[5];
  const float* end_t   = (const float*)d_in[6];
  const float* trans   = (const float*)d_in[7];
  float* out = (float*)d_out;

  float* logits  = (float*)d_ws;                      // 294912 floats
  float* segmat  = logits + (size_t)NROWS * NL;       // 64*8*81 floats
  float* num_den = segmat + (size_t)BB * NSEG * 81;   // 64 floats (num)
  int*   lens    = (int*)(num_den + 128);             // 64 ints

  hipMemsetAsync(out, 0, sizeof(float), stream);      // zero loss accumulator
  logits_kernel<<<2048, 256, 0, stream>>>(hidden, W, bias, mask, logits, lens);
  scan_kernel<<<1664, 64, 0, stream>>>(logits, labels, start_t, end_t, trans,
                                       out, num_den, lens, segmat);
  combine_kernel<<<64, 64, 0, stream>>>(logits, segmat, start_t, end_t,
                                        num_den, out);
}